// Round 8
// baseline (13106.775 us; speedup 1.0000x reference)
//
#include <hip/hip_runtime.h>

typedef __attribute__((ext_vector_type(8))) short short8;   // 8 x bf16
typedef __attribute__((ext_vector_type(4))) float f32x4;
typedef unsigned int u32;
typedef unsigned short u16;

// Problem sizes
#define SS 1024
#define BB 64
#define DD 512
#define HH 512

// ws layout (byte offsets). Total ~0x4442200 (~68.5 MB).
#define WS_XB    0x00000000ULL   // bf16 X:  65536*512*2 = 0x4000000
#define WS_WPX   0x04000000ULL   // bf16 Wx packed: 2048*512*2 = 0x200000
#define WS_WPH   0x04200000ULL   // bf16 Wh packed: 0x200000
#define WS_BIAS  0x04400000ULL   // f32 2048 = 0x2000
#define WS_HB0   0x04402000ULL   // bf16 64*512*2 = 0x20000
#define WS_HB1   0x04422000ULL   // bf16 64*512*2 = 0x20000
#define WS_BAR   0x04442000ULL   // 8 sub-counters, 64B apart

__device__ __forceinline__ u16 f2bf(float x) {
  union { float f; u32 u; } v; v.f = x;
  u32 r = v.u + 0x7fffu + ((v.u >> 16) & 1u);   // RNE
  return (u16)(r >> 16);
}

__device__ __forceinline__ float sigm(float x) {
  return 1.f / (1.f + __expf(-x));
}
__device__ __forceinline__ float tanh_fast(float x) {
  const float e = __expf(-2.f * __builtin_fabsf(x));
  return __builtin_copysignf((1.f - e) / (1.f + e), x);
}

// ---------------------------------------------------------------------------
// pack_x: fp32 X -> bf16 Xb (flat 65536x512, row = t*64+b)
// ---------------------------------------------------------------------------
__global__ __launch_bounds__(256) void pack_x(const float* __restrict__ X,
                                              u16* __restrict__ Xb) {
  const size_t i = ((size_t)blockIdx.x * 256 + threadIdx.x) * 4;
  const float4 v = *(const float4*)(X + i);
  uint2 o;
  o.x = (u32)f2bf(v.x) | ((u32)f2bf(v.y) << 16);
  o.y = (u32)f2bf(v.z) | ((u32)f2bf(v.w) << 16);
  *(uint2*)(Xb + i) = o;
}

// ---------------------------------------------------------------------------
// pack_w: repack gate weights into col' = unit*4 + gate order, bf16.
//   Wpx[c][k] = W_gate[u][k]  (x-part, k<512); Wph[c][k] = W_gate[u][512+k]
//   bias[c]   = b_gate[u]
// ---------------------------------------------------------------------------
__global__ __launch_bounds__(128) void pack_w(
    const float* __restrict__ Wf, const float* __restrict__ bf_,
    const float* __restrict__ Wi, const float* __restrict__ bi_,
    const float* __restrict__ Wg, const float* __restrict__ bg_,
    const float* __restrict__ Wo, const float* __restrict__ bo_,
    u16* __restrict__ Wpx, u16* __restrict__ Wph, float* __restrict__ bias) {
  const int c = blockIdx.x;            // 0..2047
  const int g = c & 3, u = c >> 2;
  const float* Wsrc = (g == 0 ? Wf : g == 1 ? Wi : g == 2 ? Wg : Wo) + (size_t)u * 1024;
  const int k = threadIdx.x * 4;       // 0..508
  const float4 vx = *(const float4*)(Wsrc + k);
  const float4 vh = *(const float4*)(Wsrc + 512 + k);
  uint2 ox, oh;
  ox.x = (u32)f2bf(vx.x) | ((u32)f2bf(vx.y) << 16);
  ox.y = (u32)f2bf(vx.z) | ((u32)f2bf(vx.w) << 16);
  oh.x = (u32)f2bf(vh.x) | ((u32)f2bf(vh.y) << 16);
  oh.y = (u32)f2bf(vh.z) | ((u32)f2bf(vh.w) << 16);
  *(uint2*)(Wpx + (size_t)c * 512 + k) = ox;
  *(uint2*)(Wph + (size_t)c * 512 + k) = oh;
  if (threadIdx.x == 0)
    bias[c] = (g == 0 ? bf_ : g == 1 ? bi_ : g == 2 ? bg_ : bo_)[u];
}

// ---------------------------------------------------------------------------
// Fused persistent LSTM kernel. 128 WGs x 256 thr (COOPERATIVE launch ->
// co-residency guaranteed; custom barrier used for speed). WG w owns hidden
// units 4w..4w+3 (16 packed gate-cols, m0=16w). Wave = 16-batch slice; each
// lane owns one (unit u_loc, batch brow) pair, holding f/i/g/o in its 4
// MFMA C-fragment regs (packed col' = unit*4+gate == D-row (lane>>4)*4+reg).
//
//  - Wh AND Wx A-fragments preloaded to VGPRs once (128 VGPRs).
//  - Input GEMM fused: gx[t+1] computed from X-fragments DURING the grid-
//    barrier wait of step t (off critical path); stays in registers and
//    seeds the h-GEMM accumulator (bias folded in).
//  - h double-buffered bf16 in global; B-frags read directly (L2/L3).
//  - Per-step 2-level atomic grid barrier, 8 padded sub-counters; spin is
//    BOUNDED (8192 polls, >1000x margin over a legit ~6-poll wait) so a
//    residency failure terminates with wrong results instead of hanging.
//  - Wave 0 stores ONLY the 8B hnxt state before the release-atomic (its
//    vmcnt drain is minimal); wave 1 stores `out` (+hx/cx at the end),
//    draining lazily during the spin (vmcnt is per-wave).
//
// Barrier memory model (OCKL grid-sync pattern): wave 0's RELEASE add
// orders its prior hnxt stores at agent scope; after the closing
// __syncthreads EVERY thread executes an agent-scope ACQUIRE fence, so
// each wave's next-step h loads are ordered after an invalidate.
// ---------------------------------------------------------------------------
__global__ __launch_bounds__(256, 1) void lstm_scan(
    const u16* __restrict__ Wph, const u16* __restrict__ Wpx,
    const u16* __restrict__ Xb, const float* __restrict__ bias,
    u16* __restrict__ hb0, u16* __restrict__ hb1,
    float* __restrict__ out, u32* __restrict__ bar) {
  const int w = blockIdx.x;          // 0..127
  const int tid = threadIdx.x;
  const int lane = tid & 63;
  const int wave = tid >> 6;
  const int m0 = w * 16;
  const int kq = (lane >> 4) * 8;
  const int arow = m0 + (lane & 15);
  const int brow = wave * 16 + (lane & 15);   // batch index
  const int u_loc = lane >> 4;                // 0..3 unit-within-WG

  // Preload A-fragments: Wh + Wx for this WG's 16 cols (64+64 VGPRs)
  short8 ah[16], ax[16];
#pragma unroll
  for (int kf = 0; kf < 16; ++kf) {
    ah[kf] = *(const short8*)(Wph + (size_t)arow * 512 + kf * 32 + kq);
    ax[kf] = *(const short8*)(Wpx + (size_t)arow * 512 + kf * 32 + kq);
  }
  const float4 b4 = *(const float4*)(bias + m0 + u_loc * 4);
  const f32x4 bias_acc = (f32x4){b4.x, b4.y, b4.z, b4.w};

  // Prologue: gx[0] (bias included), then start X loads for step 1.
  short8 bx[16];
#pragma unroll
  for (int kf = 0; kf < 16; ++kf)
    bx[kf] = *(const short8*)(Xb + (size_t)brow * 512 + kf * 32 + kq);
  f32x4 x0 = bias_acc, x1 = (f32x4){0.f, 0.f, 0.f, 0.f}, x2 = x1, x3 = x1;
#pragma unroll
  for (int kf = 0; kf < 16; kf += 4) {
    x0 = __builtin_amdgcn_mfma_f32_16x16x32_bf16(ax[kf + 0], bx[kf + 0], x0, 0, 0, 0);
    x1 = __builtin_amdgcn_mfma_f32_16x16x32_bf16(ax[kf + 1], bx[kf + 1], x1, 0, 0, 0);
    x2 = __builtin_amdgcn_mfma_f32_16x16x32_bf16(ax[kf + 2], bx[kf + 2], x2, 0, 0, 0);
    x3 = __builtin_amdgcn_mfma_f32_16x16x32_bf16(ax[kf + 3], bx[kf + 3], x3, 0, 0, 0);
  }
  f32x4 gxcur = (x0 + x1) + (x2 + x3);
#pragma unroll
  for (int kf = 0; kf < 16; ++kf)
    bx[kf] = *(const short8*)(Xb + ((size_t)64 + brow) * 512 + kf * 32 + kq);

  float c_reg = 0.f;   // cell state for (unit w*4+u_loc, batch brow)
  __shared__ float ho_lds[64][4];
  __shared__ float co_lds[64][4];

#pragma unroll 1
  for (int t = 0; t < SS; ++t) {
    const u16* hcur = (t & 1) ? hb1 : hb0;
    u16* hnxt = (t & 1) ? hb0 : hb1;

    // ---- critical path: h-GEMM ----
    short8 bh[16];
#pragma unroll
    for (int kf = 0; kf < 16; ++kf)
      bh[kf] = *(const short8*)(hcur + (size_t)brow * 512 + kf * 32 + kq);

    f32x4 ac0 = gxcur;                       // gx[t] + bias seeds the acc
    f32x4 ac1 = (f32x4){0.f, 0.f, 0.f, 0.f}, ac2 = ac1, ac3 = ac1;
#pragma unroll
    for (int kf = 0; kf < 16; kf += 4) {
      ac0 = __builtin_amdgcn_mfma_f32_16x16x32_bf16(ah[kf + 0], bh[kf + 0], ac0, 0, 0, 0);
      ac1 = __builtin_amdgcn_mfma_f32_16x16x32_bf16(ah[kf + 1], bh[kf + 1], ac1, 0, 0, 0);
      ac2 = __builtin_amdgcn_mfma_f32_16x16x32_bf16(ah[kf + 2], bh[kf + 2], ac2, 0, 0, 0);
      ac3 = __builtin_amdgcn_mfma_f32_16x16x32_bf16(ah[kf + 3], bh[kf + 3], ac3, 0, 0, 0);
    }
    const f32x4 accs = (ac0 + ac1) + (ac2 + ac3);

    // lane holds gates f,i,g,o (regs 0..3) for (unit, batch)
    const float fs = sigm(accs[0]);
    const float is = sigm(accs[1]);
    const float gv = tanh_fast(accs[2]);
    const float os = sigm(accs[3]);
    c_reg = fs * c_reg + is * gv;
    const float hv = os * tanh_fast(c_reg);

    ho_lds[brow][u_loc] = hv;
    co_lds[brow][u_loc] = c_reg;
    __syncthreads();

    if (tid < 64) {
      // wave 0: ONLY the bf16 h-state store (minimal release drain)
      const float4 h4 = *(const float4*)(ho_lds[tid]);
      uint2 hb;
      hb.x = (u32)f2bf(h4.x) | ((u32)f2bf(h4.y) << 16);
      hb.y = (u32)f2bf(h4.z) | ((u32)f2bf(h4.w) << 16);
      *(uint2*)(hnxt + (size_t)tid * 512 + w * 4) = hb;
    } else if (tid < 128) {
      // wave 1: out store — off the release path, drains during spin
      const int b = tid - 64;
      const float4 h4 = *(const float4*)(ho_lds[b]);
      *(float4*)(out + (size_t)t * 32768 + (size_t)b * 512 + w * 4) = h4;
      if (t == SS - 1) {
        *(float4*)(out + 33554432 + (size_t)b * 512 + w * 4) = h4;   // hx
        const float4 c4 = *(const float4*)(co_lds[b]);
        *(float4*)(out + 33554432 + 32768 + (size_t)b * 512 + w * 4) = c4;  // cx
      }
    }

    if (t != SS - 1) {
      // release: bump sub-counter (orders wave-0's hnxt stores, agent scope)
      if (tid == 0)
        __hip_atomic_fetch_add(bar + (blockIdx.x & 7) * 16, 1u,
                               __ATOMIC_RELEASE, __HIP_MEMORY_SCOPE_AGENT);
      __builtin_amdgcn_sched_barrier(0);   // keep x-work below the release

      // ---- off-critical path (hidden under barrier wait) ----
      // x-GEMM producing gx[t+1] from bx loaded last iteration
      x0 = bias_acc; x1 = (f32x4){0.f, 0.f, 0.f, 0.f}; x2 = x1; x3 = x1;
#pragma unroll
      for (int kf = 0; kf < 16; kf += 4) {
        x0 = __builtin_amdgcn_mfma_f32_16x16x32_bf16(ax[kf + 0], bx[kf + 0], x0, 0, 0, 0);
        x1 = __builtin_amdgcn_mfma_f32_16x16x32_bf16(ax[kf + 1], bx[kf + 1], x1, 0, 0, 0);
        x2 = __builtin_amdgcn_mfma_f32_16x16x32_bf16(ax[kf + 2], bx[kf + 2], x2, 0, 0, 0);
        x3 = __builtin_amdgcn_mfma_f32_16x16x32_bf16(ax[kf + 3], bx[kf + 3], x3, 0, 0, 0);
      }
      gxcur = (x0 + x1) + (x2 + x3);
      // issue X-fragment loads for step t+2 (consumed next iteration)
      const size_t tnx = (size_t)((t + 2 < SS) ? t + 2 : SS - 1) * 64 + brow;
#pragma unroll
      for (int kf = 0; kf < 16; ++kf)
        bx[kf] = *(const short8*)(Xb + tnx * 512 + kf * 32 + kq);

      // parallel spin: lanes 0..7 each watch one sub-counter. BOUNDED so a
      // co-residency failure terminates (wrong results) instead of hanging.
      const u32 target = (u32)(t + 1) * 16u;   // 128 WGs / 8 subs
      if (tid < 8) {
        int guard = 0;
#pragma unroll 1
        while (__hip_atomic_load(bar + tid * 16, __ATOMIC_RELAXED,
                                 __HIP_MEMORY_SCOPE_AGENT) < target &&
               ++guard < 8192)
          __builtin_amdgcn_s_sleep(1);
      }
      __syncthreads();
      // acquire: every thread orders its next-step h loads after an inv
      __builtin_amdgcn_fence(__ATOMIC_ACQUIRE, "agent");
    }
  }
}

// ---------------------------------------------------------------------------
extern "C" void kernel_launch(void* const* d_in, const int* in_sizes, int n_in,
                              void* d_out, int out_size, void* d_ws, size_t ws_size,
                              hipStream_t stream) {
  const float* X  = (const float*)d_in[0];
  const float* Wf = (const float*)d_in[1];
  const float* bf_ = (const float*)d_in[2];
  const float* Wi = (const float*)d_in[3];
  const float* bi_ = (const float*)d_in[4];
  const float* Wg = (const float*)d_in[5];
  const float* bg_ = (const float*)d_in[6];
  const float* Wo = (const float*)d_in[7];
  const float* bo_ = (const float*)d_in[8];

  char* ws = (char*)d_ws;
  u16*   Xb   = (u16*)(ws + WS_XB);
  u16*   Wpx  = (u16*)(ws + WS_WPX);
  u16*   Wph  = (u16*)(ws + WS_WPH);
  float* bias = (float*)(ws + WS_BIAS);
  u16*   hb0  = (u16*)(ws + WS_HB0);
  u16*   hb1  = (u16*)(ws + WS_HB1);
  u32*   bar  = (u32*)(ws + WS_BAR);
  float* outp = (float*)d_out;

  // zero h0 double-buffers + barrier counters (ws re-poisoned each call)
  hipMemsetAsync(ws + WS_HB0, 0, 0x20000 * 2 + 512, stream);

  pack_x<<<32768, 256, 0, stream>>>(X, Xb);
  pack_w<<<2048, 128, 0, stream>>>(Wf, bf_, Wi, bi_, Wg, bg_, Wo, bo_, Wpx, Wph, bias);

  // Cooperative launch -> guaranteed co-residency for the custom grid barrier.
  // Fallback to a plain launch if cooperative isn't available in this context.
  void* args[] = {(void*)&Wph, (void*)&Wpx, (void*)&Xb, (void*)&bias,
                  (void*)&hb0, (void*)&hb1, (void*)&outp, (void*)&bar};
  hipError_t rc = hipLaunchCooperativeKernel((const void*)lstm_scan,
                                             dim3(128), dim3(256),
                                             args, 0, stream);
  if (rc != hipSuccess) {
    lstm_scan<<<128, 256, 0, stream>>>(Wph, Wpx, Xb, bias, hb0, hb1, outp, bar);
  }
}